// Round 8
// baseline (1275.070 us; speedup 1.0000x reference)
//
#include <hip/hip_runtime.h>
#include <hip/hip_bf16.h>
#include <cstdint>
#include <cstddef>

#define B_ 32
#define C_ 256
#define S_ 1024
#define L_ 8

typedef unsigned short bf16_t;
typedef __attribute__((ext_vector_type(8))) short s8v;   // 8 bf16 (16B)
typedef __attribute__((ext_vector_type(4))) short s4v;   // 4 bf16 (8B)
typedef __attribute__((ext_vector_type(4))) float f4v;

static __device__ __forceinline__ float b2f(bf16_t v) {
    unsigned int u = ((unsigned int)v) << 16;
    float f;
    __builtin_memcpy(&f, &u, 4);
    return f;
}
static __device__ __forceinline__ bf16_t f2b(float f) {
    unsigned int u;
    __builtin_memcpy(&u, &f, 4);
    u += 0x7fffu + ((u >> 16) & 1u);
    return (bf16_t)(u >> 16);
}
static __device__ __forceinline__ float sigmoidf_(float x) {
    return 1.0f / (1.0f + __expf(-x));
}
static __device__ __forceinline__ void gload_lds16(const void* g, void* l) {
    __builtin_amdgcn_global_load_lds((const __attribute__((address_space(1))) void*)g,
                                     (__attribute__((address_space(3))) void*)l, 16, 0, 0);
}

// ---------------- prologue kernels ----------------

__global__ void fuse_wb_k(const float* __restrict__ cw, const float* __restrict__ cb,
                          const float* __restrict__ fwm, const float* __restrict__ fbv,
                          float* __restrict__ fw, float* __restrict__ fb) {
    int c = threadIdx.x;
    float a = 0.f, bs = 0.f;
    for (int o = 0; o < C_; o++) {
        float f = fwm[o * C_ + c];
        a += cw[o] * f;
        bs += cb[o] * f;
    }
    fw[c] = a;
    fb[c] = bs + fbv[c];
}

// Transposed bf16 weights WT[(l*6+tp)][m][k]; tp: 0=q 1=k 2=v 3=f 4=wa_even 5=wa_odd.
// q/k/v rows get pre-scaled by ln gamma: W'[k][m] = g[k]*W[k][m]  (LN fold).
__global__ __launch_bounds__(256) void wtrans_k(const float* __restrict__ wq, const float* __restrict__ wk,
                                                const float* __restrict__ wv, const float* __restrict__ wf,
                                                const float* __restrict__ wa, const float* __restrict__ ln_s,
                                                bf16_t* __restrict__ WT) {
    __shared__ float t[32][33];
    int z = blockIdx.z, l = z / 6, tp = z - l * 6;
    const float* src;
    int ld, cmul, coff;
    if (tp < 4) {
        const float* bases[4] = {wq, wk, wv, wf};
        src = bases[tp] + (size_t)l * 65536;
        ld = 256; cmul = 1; coff = 0;
    } else {
        src = wa + (size_t)l * 131072;
        ld = 512; cmul = 2; coff = tp - 4;
    }
    const float* g = ln_s + l * 256;
    bf16_t* dst = WT + ((size_t)l * 6 + tp) * 65536;
    int k0 = blockIdx.y * 32, m0 = blockIdx.x * 32;
    int tx = threadIdx.x & 31, ty = threadIdx.x >> 5;
#pragma unroll
    for (int r = 0; r < 4; ++r) {
        int k = k0 + ty + 8 * r;
        float v = src[(size_t)k * ld + (m0 + tx) * cmul + coff];
        if (tp < 3) v *= g[k];
        t[ty + 8 * r][tx] = v;
    }
    __syncthreads();
#pragma unroll
    for (int r = 0; r < 4; ++r)
        dst[(size_t)(m0 + ty + 8 * r) * 256 + k0 + tx] = f2b(t[tx][ty + 8 * r]);
}

// Per (layer, mat in {q,k,v}, m): csum[m] = sum_k W'[m][k] (from WT),
// bias2[m] = b[m] + sum_k ln_b[k]*W[k][m] (from original fp32 weights).
__global__ __launch_bounds__(256) void colsum_k(const bf16_t* __restrict__ WT,
                                                const float* __restrict__ wq, const float* __restrict__ wk,
                                                const float* __restrict__ wv,
                                                const float* __restrict__ bq, const float* __restrict__ bk,
                                                const float* __restrict__ bv,
                                                const float* __restrict__ ln_b,
                                                float* __restrict__ csum, float* __restrict__ bias2) {
    int m = threadIdx.x, mat = blockIdx.x, l = blockIdx.y;
    const bf16_t* wt = WT + ((size_t)l * 6 + mat) * 65536 + (size_t)m * 256;
    float cs = 0.f;
    for (int k = 0; k < 256; k += 8) {
        s8v u = *(const s8v*)(wt + k);
#pragma unroll
        for (int j = 0; j < 8; ++j) cs += b2f((bf16_t)u[j]);
    }
    const float* worig = (mat == 0 ? wq : mat == 1 ? wk : wv) + (size_t)l * 65536;
    const float* borig = (mat == 0 ? bq : mat == 1 ? bk : bv) + l * 256;
    const float* lb = ln_b + l * 256;
    float bb = 0.f;
    for (int k = 0; k < 256; ++k) bb += lb[k] * worig[(size_t)k * 256 + m];
    int o = (l * 3 + mat) * 256 + m;
    csum[o] = cs;
    bias2[o] = bb + borig[m];
}

// X[b][s][c] = tanh(img_pixel(b,s)*fw[c]+fb[c])  -- (B,S,C) bf16, wave per row.
// Seeds PART[row][0]=(sum,sq), PART[row][1..7]=0  (8 float2 = 64B per row).
__global__ __launch_bounds__(256) void embed_k(const float* __restrict__ img, const float* __restrict__ fw,
                                               const float* __restrict__ fb, bf16_t* __restrict__ X,
                                               float* __restrict__ PART) {
    int wid = threadIdx.x >> 6, lane = threadIdx.x & 63;
    int row = blockIdx.x * 4 + wid;          // b*1024+s
    int b = row >> 10, s = row & 1023;
    float xv = img[(size_t)b * 262144 + (size_t)(s >> 5) * 8192 + (s & 31) * 16];
    f4v fwv = *(const f4v*)(fw + lane * 4);
    f4v fbv = *(const f4v*)(fb + lane * 4);
    s4v o;
    float sum = 0.f, sq = 0.f;
#pragma unroll
    for (int j = 0; j < 4; ++j) {
        float v = tanhf(xv * fwv[j] + fbv[j]);
        float vb = b2f(f2b(v));  // stats on the stored bf16 value
        o[j] = (short)f2b(v);
        sum += vb;
        sq += vb * vb;
    }
    *(s4v*)(X + (size_t)row * 256 + lane * 4) = o;
#pragma unroll
    for (int off = 32; off > 0; off >>= 1) {
        sum += __shfl_xor(sum, off);
        sq += __shfl_xor(sq, off);
    }
    float sb = __shfl(sum, 0), qb = __shfl(sq, 0);
    if (lane < 8) {
        float2 v = (lane == 0) ? make_float2(sb, qb) : make_float2(0.f, 0.f);
        *(float2*)(PART + (size_t)row * 16 + lane * 2) = v;
    }
}

// ---------------- MFMA GEMM (proven tiling: BM=128, BN=64, BK=64) ----------------
// MODE 0: QKV stacked (M=768) on RAW x with LN fold (stats combined from PART[row][0..7]) ->
//         (B,C,S) Q/K/V via LDS-transpose epilogue.
// MODE 1: gate dual: tn2 = sig(acc0+ba[2m])*ta + sig(acc1+ba[2m+1]) -> O0 (B,S,C).
// MODE 2: wf: x = relu(acc+bf)+ta -> O0 (B,S,C), optional fp32 hid; writes per-row
//         partial (sum,sq) of its 64-col slice into partOut[row][blockIdx.x*2+wcol].
template <int MODE, bool HID>
__global__ __launch_bounds__(256) void mm_k(const bf16_t* Ain,
                                            const bf16_t* __restrict__ W0,
                                            const bf16_t* __restrict__ W1,
                                            const float* __restrict__ bias0,
                                            const float* __restrict__ csP,
                                            const float* __restrict__ PART,
                                            const bf16_t* ta,
                                            bf16_t* O0, bf16_t* O1, bf16_t* O2,
                                            float* __restrict__ hid,
                                            float* __restrict__ partOut) {
    constexpr int LDSZ = (MODE == 0) ? 34816 : 32768;
    __shared__ char lds[LDSZ];
    char* XS = lds;             // [128 rows][128B]
    char* WS0 = lds + 16384;    // [64 rows][128B]
    char* WS1 = lds + 24576;    // MODE1 only
    const int tid = threadIdx.x, lane = tid & 63, wid = tid >> 6;
    const int wrow = wid >> 1, wcol = wid & 1;
    const int s0 = blockIdx.y * 128, mt0 = blockIdx.x * 64, b = blockIdx.z;

    if constexpr (MODE == 0) {
        // pre-phase: combine 8 partials per row -> (rs, rs*mu) in LDS (region after WS0, unused in MODE0)
        float2* stats = (float2*)(lds + 24576);
        if (tid < 128) {
            int sg = b * 1024 + s0 + tid;
            const float* pp = PART + (size_t)sg * 16;
            f4v p0 = *(const f4v*)pp;
            f4v p1 = *(const f4v*)(pp + 4);
            f4v p2 = *(const f4v*)(pp + 8);
            f4v p3 = *(const f4v*)(pp + 12);
            float su = p0[0] + p0[2] + p1[0] + p1[2] + p2[0] + p2[2] + p3[0] + p3[2];
            float qq = p0[1] + p0[3] + p1[1] + p1[3] + p2[1] + p2[3] + p3[1] + p3[3];
            float mu = su * (1.f / 256.f);
            float var = qq * (1.f / 256.f) - mu * mu;
            float rsv = rsqrtf(var + 1e-5f);
            stats[tid] = make_float2(rsv, rsv * mu);
        }
    }

    const int lr8 = lane >> 3;
    const int cb0 = ((lane & 7) << 4) ^ (lr8 << 4);  // pre-swizzled source col byte

    const char* Ag = (const char*)Ain + (((size_t)b * 1024 + s0) * 256) * 2 + cb0;
    const char* Wg0 = (const char*)W0 + ((size_t)mt0 * 256) * 2 + cb0;
    const char* Wg1 = (const char*)W1 + ((size_t)mt0 * 256) * 2 + cb0;

    f4v acc[4][2] = {};
    f4v acc1[4][2] = {};

    for (int kt = 0; kt < 4; ++kt) {
        const char* ga = Ag + kt * 128;
#pragma unroll
        for (int q = 0; q < 4; ++q) {
            int r0 = wid * 32 + q * 8;
            gload_lds16(ga + (size_t)(r0 + lr8) * 512, XS + r0 * 128);
        }
        const char* gw = Wg0 + kt * 128;
#pragma unroll
        for (int p = 0; p < 2; ++p) {
            int r0 = wid * 16 + p * 8;
            gload_lds16(gw + (size_t)(r0 + lr8) * 512, WS0 + r0 * 128);
        }
        if constexpr (MODE == 1) {
            const char* gw1 = Wg1 + kt * 128;
#pragma unroll
            for (int p = 0; p < 2; ++p) {
                int r0 = wid * 16 + p * 8;
                gload_lds16(gw1 + (size_t)(r0 + lr8) * 512, WS1 + r0 * 128);
            }
        }
        __syncthreads();
#pragma unroll
        for (int kk = 0; kk < 2; ++kk) {
            const int cb = kk * 64 + ((lane >> 4) << 4);
            s8v av[4];
#pragma unroll
            for (int mi = 0; mi < 4; ++mi) {
                int r = wrow * 64 + mi * 16 + (lane & 15);
                av[mi] = *(const s8v*)(XS + r * 128 + (cb ^ ((r & 7) << 4)));
            }
            s8v bv[2], bw[2];
#pragma unroll
            for (int ni = 0; ni < 2; ++ni) {
                int m = wcol * 32 + ni * 16 + (lane & 15);
                bv[ni] = *(const s8v*)(WS0 + m * 128 + (cb ^ ((m & 7) << 4)));
                if constexpr (MODE == 1)
                    bw[ni] = *(const s8v*)(WS1 + m * 128 + (cb ^ ((m & 7) << 4)));
            }
#pragma unroll
            for (int mi = 0; mi < 4; ++mi)
#pragma unroll
                for (int ni = 0; ni < 2; ++ni) {
                    acc[mi][ni] = __builtin_amdgcn_mfma_f32_16x16x32_bf16(av[mi], bv[ni], acc[mi][ni], 0, 0, 0);
                    if constexpr (MODE == 1)
                        acc1[mi][ni] = __builtin_amdgcn_mfma_f32_16x16x32_bf16(av[mi], bw[ni], acc1[mi][ni], 0, 0, 0);
                }
        }
        __syncthreads();
    }

    if constexpr (MODE == 0) {
        const int mat = mt0 >> 8, mw = mt0 & 255;
        const float* bs = bias0 + mat * 256 + mw;
        const float* cs = csP + mat * 256 + mw;
        bf16_t* Os = (mat == 0) ? O0 : (mat == 1 ? O1 : O2);
        const float2* stats = (const float2*)(lds + 24576);
        bf16_t* T = (bf16_t*)lds;  // [64][144]
#pragma unroll
        for (int mi = 0; mi < 4; ++mi)
#pragma unroll
            for (int r = 0; r < 4; ++r) {
                int sl = wrow * 64 + mi * 16 + (lane >> 4) * 4 + r;
                float2 st = stats[sl];
                float a = st.x, cc = st.y;
#pragma unroll
                for (int ni = 0; ni < 2; ++ni) {
                    int ml = wcol * 32 + ni * 16 + (lane & 15);
                    float v = sigmoidf_(a * acc[mi][ni][r] - cc * cs[ml] + bs[ml]);
                    T[ml * 144 + sl] = f2b(v);
                }
            }
        __syncthreads();
        int m = tid >> 2, c0s = (tid & 3) * 32;
        bf16_t* dst = Os + ((size_t)(b * 256 + mw + m)) * 1024 + s0 + c0s;
#pragma unroll
        for (int j = 0; j < 4; ++j)
            *(s8v*)(dst + j * 8) = *(const s8v*)(T + m * 144 + c0s + j * 8);
    } else if constexpr (MODE == 1) {
#pragma unroll
        for (int mi = 0; mi < 4; ++mi)
#pragma unroll
            for (int ni = 0; ni < 2; ++ni) {
                int ml = mt0 + wcol * 32 + ni * 16 + (lane & 15);
#pragma unroll
                for (int r = 0; r < 4; ++r) {
                    int sg = b * 1024 + s0 + wrow * 64 + mi * 16 + (lane >> 4) * 4 + r;
                    size_t idx = (size_t)sg * 256 + ml;
                    float v = sigmoidf_(acc[mi][ni][r] + bias0[2 * ml]) * b2f(ta[idx]) +
                              sigmoidf_(acc1[mi][ni][r] + bias0[2 * ml + 1]);
                    O0[idx] = f2b(v);
                }
            }
    } else {
#pragma unroll
        for (int mi = 0; mi < 4; ++mi)
#pragma unroll
            for (int r = 0; r < 4; ++r) {
                int sg = b * 1024 + s0 + wrow * 64 + mi * 16 + (lane >> 4) * 4 + r;
                float vv[2];
#pragma unroll
                for (int ni = 0; ni < 2; ++ni) {
                    int ml = mt0 + wcol * 32 + ni * 16 + (lane & 15);
                    size_t idx = (size_t)sg * 256 + ml;
                    float v = fmaxf(acc[mi][ni][r] + bias0[ml], 0.f) + b2f(ta[idx]);
                    O0[idx] = f2b(v);
                    if constexpr (HID) hid[idx] = v;
                    vv[ni] = v;
                }
                // per-row partial over this wave's 32 cols -> indexed slot (no atomics)
                float ps = vv[0] + vv[1];
                float pq = vv[0] * vv[0] + vv[1] * vv[1];
                ps += __shfl_xor(ps, 1); pq += __shfl_xor(pq, 1);
                ps += __shfl_xor(ps, 2); pq += __shfl_xor(pq, 2);
                ps += __shfl_xor(ps, 4); pq += __shfl_xor(pq, 4);
                ps += __shfl_xor(ps, 8); pq += __shfl_xor(pq, 8);
                if ((lane & 15) == 0)
                    *(float2*)(partOut + (size_t)sg * 16 + (blockIdx.x * 2 + wcol) * 2) =
                        make_float2(ps, pq);
            }
    }
}

// ---------------- fused attention + transpose-add (MFMA) ----------------
// Block = (b, 16-channel group), 512 threads (8 waves). Each wave runs the per-channel
// pipeline for channels c0+8k+w, k=0..1; after each k, block-wide phase does
// X[b,s,c0+8k..+7] += out^T (16B contiguous) with optional fp32 att snapshot.
// Per-wave LDS region 8976B (stride chosen so w-regions land in distinct banks).
template <bool SNAP>
__global__ __launch_bounds__(512) void attnf_k(const bf16_t* __restrict__ Q, const bf16_t* __restrict__ K,
                                               const bf16_t* __restrict__ V, bf16_t* __restrict__ Xp,
                                               float* __restrict__ att) {
    __shared__ char Lds[71808];
    const int w = threadIdx.x >> 6, lane = threadIdx.x & 63;
    char* P = Lds + w * 8976;
    const int b = blockIdx.x >> 4, g = blockIdx.x & 15;
    const int c0 = g * 16;
    constexpr int VT = 0, S1 = 2560, S2 = 5120, KQ = 6400;
    const f4v zf = {0.f, 0.f, 0.f, 0.f};
    const int frow = lane & 15, fhalf = lane >> 4;
    const int fbyte = fhalf * 16;

    // one-time zero fills of pad regions (wave-private; persist across k)
    if (lane < 32) {
#pragma unroll
        for (int q = 0; q < 4; ++q) *(f4v*)(P + S1 + lane * 80 + q * 16) = zf;       // s1 rows full 64B
#pragma unroll
        for (int q = 0; q < 3; ++q) *(f4v*)(P + KQ + lane * 80 + 16 + q * 16) = zf;  // kqvT k-pad
    } else if (lane < 40) {
#pragma unroll
        for (int q = 0; q < 4; ++q) *(f4v*)(P + S2 + (lane - 24) * 80 + q * 16) = zf;  // s2 rows 8..15
    }

    for (int k = 0; k < 2; ++k) {
        const int c = c0 + 8 * k + w;
        const size_t base = ((size_t)b * 256 + c) * 1024;
        const bf16_t* Qg = Q + base;
        const bf16_t* Kg = K + base;
        const bf16_t* Vg = V + base;

        // fragments direct from global (rows = 32 bf16 = 64B contiguous)
        s8v aq0 = *(const s8v*)(Qg + frow * 32 + fhalf * 8);
        s8v aq1 = *(const s8v*)(Qg + (16 + frow) * 32 + fhalf * 8);
        s8v bk0 = *(const s8v*)(Kg + frow * 32 + fhalf * 8);
        s8v bk1 = *(const s8v*)(Kg + (16 + frow) * 32 + fhalf * 8);
        // pooled fragments in registers (rows clamped; rows>=8 garbage, discarded downstream)
        float accq[8], acck[8];
#pragma unroll
        for (int j = 0; j < 8; ++j) { accq[j] = 0.f; acck[j] = 0.f; }
#pragma unroll
        for (int pp = 0; pp < 4; ++pp) {
            int rr = 4 * frow + pp;
            if (rr > 31) rr = 31;
            s8v uq = *(const s8v*)(Qg + rr * 32 + fhalf * 8);
            s8v uk = *(const s8v*)(Kg + rr * 32 + fhalf * 8);
#pragma unroll
            for (int j = 0; j < 8; ++j) {
                accq[j] += b2f((bf16_t)uq[j]);
                acck[j] += b2f((bf16_t)uk[j]);
            }
        }
        s8v aqp, bkp;
#pragma unroll
        for (int j = 0; j < 8; ++j) {
            aqp[j] = (short)f2b(accq[j] * 0.25f);
            bkp[j] = (short)f2b(acck[j] * 0.25f);
        }
        // V load + LDS transpose staging into VT
        {
            s8v v0 = *(const s8v*)(Vg + lane * 16);
            s8v v1 = *(const s8v*)(Vg + lane * 16 + 8);
            int pw = lane >> 1, ph0 = (lane & 1) * 16;
#pragma unroll
            for (int j = 0; j < 8; ++j) {
                *(bf16_t*)(P + VT + (ph0 + j) * 80 + pw * 2) = (bf16_t)(unsigned short)v0[j];
                *(bf16_t*)(P + VT + (ph0 + 8 + j) * 80 + pw * 2) = (bf16_t)(unsigned short)v1[j];
            }
        }

        // stage 1&2 MFMAs (register inputs only)
        f4v s1a = __builtin_amdgcn_mfma_f32_16x16x32_bf16(aq0, bkp, zf, 0, 0, 0);
        f4v s1b = __builtin_amdgcn_mfma_f32_16x16x32_bf16(aq1, bkp, zf, 0, 0, 0);
        f4v s2a = __builtin_amdgcn_mfma_f32_16x16x32_bf16(aqp, bk0, zf, 0, 0, 0);
        f4v s2b = __builtin_amdgcn_mfma_f32_16x16x32_bf16(aqp, bk1, zf, 0, 0, 0);

        const float dsc = 0.0625f;  // 1/sqrt(256)
        // softmax s1 (32 rows, valid cols j<8) -> S1 bytes 0..15 of each row
        {
            int j = lane & 15;
#pragma unroll
            for (int t = 0; t < 2; ++t) {
                f4v av = t ? s1b : s1a;
#pragma unroll
                for (int r = 0; r < 4; ++r) {
                    float x = av[r] * dsc;
                    float m = x;
                    m = fmaxf(m, __shfl_xor(m, 1));
                    m = fmaxf(m, __shfl_xor(m, 2));
                    m = fmaxf(m, __shfl_xor(m, 4));
                    float e2 = __expf(x - m);
                    float s = e2;
                    s += __shfl_xor(s, 1);
                    s += __shfl_xor(s, 2);
                    s += __shfl_xor(s, 4);
                    float p = e2 / s;
                    if (j < 8) {
                        int row = t * 16 + fhalf * 4 + r;
                        *(bf16_t*)(P + S1 + row * 80 + j * 2) = f2b(p);
                    }
                }
            }
        }
        // softmax s2 (valid rows i2<8, 32 cols across two tiles) -> S2 rows 0..7
#pragma unroll
        for (int r = 0; r < 4; ++r) {
            float xa = s2a[r] * dsc, xb = s2b[r] * dsc;
            float m = fmaxf(xa, xb);
            m = fmaxf(m, __shfl_xor(m, 1));
            m = fmaxf(m, __shfl_xor(m, 2));
            m = fmaxf(m, __shfl_xor(m, 4));
            m = fmaxf(m, __shfl_xor(m, 8));
            float ea = __expf(xa - m), eb = __expf(xb - m);
            float s = ea + eb;
            s += __shfl_xor(s, 1);
            s += __shfl_xor(s, 2);
            s += __shfl_xor(s, 4);
            s += __shfl_xor(s, 8);
            float inv = 1.f / s;
            if (lane < 32) {
                int row = fhalf * 4 + r;
                *(bf16_t*)(P + S2 + row * 80 + frow * 2) = f2b(ea * inv);
                *(bf16_t*)(P + S2 + row * 80 + (16 + frow) * 2) = f2b(eb * inv);
            }
        }
        __builtin_amdgcn_wave_barrier();
        // stage 3: kqv = s2·V -> kqv^T into KQ
        {
            s8v as2 = *(const s8v*)(P + S2 + frow * 80 + fbyte);
            s8v bv0 = *(const s8v*)(P + VT + frow * 80 + fbyte);
            s8v bv1 = *(const s8v*)(P + VT + (16 + frow) * 80 + fbyte);
            f4v k3a = __builtin_amdgcn_mfma_f32_16x16x32_bf16(as2, bv0, zf, 0, 0, 0);
            f4v k3b = __builtin_amdgcn_mfma_f32_16x16x32_bf16(as2, bv1, zf, 0, 0, 0);
            if (lane < 32) {
#pragma unroll
                for (int r = 0; r < 4; ++r) {
                    int i2 = fhalf * 4 + r;
                    *(bf16_t*)(P + KQ + frow * 80 + i2 * 2) = f2b(k3a[r]);
                    *(bf16_t*)(P + KQ + (16 + frow) * 80 + i2 * 2) = f2b(k3b[r]);
                }
            }
        }
        __builtin_amdgcn_wave_barrier();
        // stage 4: out = s1·kqv -> out tile into VT (overwrites V staging)
        {
            s8v a40 = *(const s8v*)(P + S1 + frow * 80 + fbyte);
            s8v a41 = *(const s8v*)(P + S1 + (16 + frow) * 80 + fbyte);
            s8v b40 = *(const s8v*)(P + KQ + frow * 80 + fbyte);
            s8v b41 = *(const s8v*)(P + KQ + (16 + frow) * 80 + fbyte);
            f4v o00 = __builtin_amdgcn_mfma_f32_16x16x32_bf16(a40, b40, zf, 0, 0, 0);
            f4v o01 = __builtin_amdgcn_mfma_f32_16x16x32_bf16(a40, b41, zf, 0, 0, 0);
            f4v o10 = __builtin_amdgcn_mfma_f32_16x16x32_bf16(a41, b40, zf, 0, 0, 0);
            f4v o11 = __builtin_amdgcn_mfma_f32_16x16x32_bf16(a41, b41, zf, 0, 0, 0);
#pragma unroll
            for (int r = 0; r < 4; ++r) {
                int r0 = fhalf * 4 + r;
                *(bf16_t*)(P + VT + r0 * 80 + frow * 2) = f2b(o00[r]);
                *(bf16_t*)(P + VT + r0 * 80 + (16 + frow) * 2) = f2b(o01[r]);
                *(bf16_t*)(P + VT + (16 + r0) * 80 + frow * 2) = f2b(o10[r]);
                *(bf16_t*)(P + VT + (16 + r0) * 80 + (16 + frow) * 2) = f2b(o11[r]);
            }
        }
        __syncthreads();
        // block-wide update: X[b,s,c0+8k..+7] += out^T  (gather 8 waves' VT tiles)
        {
            const int cbase = c0 + 8 * k;
            for (int t = threadIdx.x; t < 1024; t += 512) {
                int off = (t >> 5) * 80 + (t & 31) * 2;
                s8v avv;
#pragma unroll
                for (int w2 = 0; w2 < 8; ++w2)
                    avv[w2] = *(const short*)(Lds + w2 * 8976 + off);
                size_t xi = ((size_t)(b * 1024 + t)) * 256 + cbase;
                s8v xv = *(const s8v*)(Xp + xi);
                s8v nx;
                f4v lo, hi;
#pragma unroll
                for (int j = 0; j < 8; ++j) {
                    float v = b2f((bf16_t)xv[j]) + b2f((bf16_t)avv[j]);
                    nx[j] = (short)f2b(v);
                    if (j < 4) lo[j] = v; else hi[j - 4] = v;
                }
                *(s8v*)(Xp + xi) = nx;
                if constexpr (SNAP) {
                    *(f4v*)(att + xi) = lo;
                    *(f4v*)(att + xi + 4) = hi;
                }
            }
        }
        __syncthreads();  // VT reads done before next k overwrites
    }
}

// ---------------- launch ----------------

extern "C" void kernel_launch(void* const* d_in, const int* in_sizes, int n_in,
                              void* d_out, int out_size, void* d_ws, size_t ws_size,
                              hipStream_t stream) {
    const float* image  = (const float*)d_in[0];
    const float* conv_w = (const float*)d_in[1];
    const float* conv_b = (const float*)d_in[2];
    const float* feat_w = (const float*)d_in[3];
    const float* feat_b = (const float*)d_in[4];
    const float* ln_s   = (const float*)d_in[5];
    const float* ln_b   = (const float*)d_in[6];
    const float* wq     = (const float*)d_in[7];
    const float* bq     = (const float*)d_in[8];
    const float* wk     = (const float*)d_in[9];
    const float* bk     = (const float*)d_in[10];
    const float* wv     = (const float*)d_in[11];
    const float* bv     = (const float*)d_in[12];
    const float* wf     = (const float*)d_in[13];
    const float* bfv    = (const float*)d_in[14];
    const float* wa     = (const float*)d_in[15];
    const float* ba     = (const float*)d_in[16];
    float* out = (float*)d_out;

    char* p = (char*)d_ws;
    const size_t MB16 = (size_t)B_ * S_ * C_ * sizeof(bf16_t);  // 16777216
    float* fw    = (float*)p;  p += 1024;
    float* fb    = (float*)p;  p += 1024;
    float* PART  = (float*)p;  p += 2097152;   // 32768 rows x 8 float2 (64B/row)
    float* csum  = (float*)p;  p += 24576;
    float* bias2 = (float*)p;  p += 24576;
    bf16_t* WT = (bf16_t*)p;   p += (size_t)48 * 65536 * 2;
    bf16_t* X  = (bf16_t*)p;   p += MB16;
    bf16_t* T2 = (bf16_t*)p;   p += MB16;  // tn2
    bf16_t* Qb = (bf16_t*)p;   p += MB16;
    bf16_t* Kb = (bf16_t*)p;   p += MB16;
    bf16_t* Vb = (bf16_t*)p;   p += MB16;
    size_t needed = (size_t)(p - (char*)d_ws);
    if (ws_size < needed) Vb = (bf16_t*)d_out;  // out slot0 only written at the very end

    fuse_wb_k<<<1, 256, 0, stream>>>(conv_w, conv_b, feat_w, feat_b, fw, fb);
    wtrans_k<<<dim3(8, 8, 48), 256, 0, stream>>>(wq, wk, wv, wf, wa, ln_s, WT);
    colsum_k<<<dim3(3, 8), 256, 0, stream>>>(WT, wq, wk, wv, bq, bk, bv, ln_b, csum, bias2);
    embed_k<<<8192, 256, 0, stream>>>(image, fw, fb, X, PART);

    const size_t slot = (size_t)B_ * S_ * C_;

    for (int l = 0; l < L_; ++l) {
        const bf16_t* WTl = WT + (size_t)l * 6 * 65536;
        int snap = (l == 2) ? 0 : (l == 4) ? 1 : (l == 6) ? 2 : -1;

        mm_k<0, false><<<dim3(12, 8, 32), 256, 0, stream>>>(
            X, WTl, nullptr, bias2 + l * 768, csum + l * 768, PART, nullptr,
            Qb, Kb, Vb, nullptr, nullptr);
        if (snap >= 0)
            attnf_k<true><<<512, 512, 0, stream>>>(Qb, Kb, Vb, X, out + (size_t)(4 + snap) * slot);
        else
            attnf_k<false><<<512, 512, 0, stream>>>(Qb, Kb, Vb, X, nullptr);
        // X is now ta
        mm_k<1, false><<<dim3(4, 8, 32), 256, 0, stream>>>(
            X, WTl + 4 * 65536, WTl + 5 * 65536, ba + l * 512, nullptr, nullptr, X,
            T2, nullptr, nullptr, nullptr, nullptr);
        float* hid = (snap >= 0) ? out + (size_t)(1 + snap) * slot : (l == 7 ? out : nullptr);
        if (hid)
            mm_k<2, true><<<dim3(4, 8, 32), 256, 0, stream>>>(
                T2, WTl + 3 * 65536, nullptr, bfv + l * 256, nullptr, nullptr, X,
                X, nullptr, nullptr, hid, PART);
        else
            mm_k<2, false><<<dim3(4, 8, 32), 256, 0, stream>>>(
                T2, WTl + 3 * 65536, nullptr, bfv + l * 256, nullptr, nullptr, X,
                X, nullptr, nullptr, nullptr, PART);
    }
}

// Round 9
// 990.659 us; speedup vs baseline: 1.2871x; 1.2871x over previous
//
#include <hip/hip_runtime.h>
#include <hip/hip_bf16.h>
#include <cstdint>
#include <cstddef>

#define B_ 32
#define C_ 256
#define S_ 1024
#define L_ 8

typedef unsigned short bf16_t;
typedef __attribute__((ext_vector_type(8))) short s8v;   // 8 bf16 (16B)
typedef __attribute__((ext_vector_type(4))) short s4v;   // 4 bf16 (8B)
typedef __attribute__((ext_vector_type(4))) float f4v;

static __device__ __forceinline__ float b2f(bf16_t v) {
    unsigned int u = ((unsigned int)v) << 16;
    float f;
    __builtin_memcpy(&f, &u, 4);
    return f;
}
static __device__ __forceinline__ bf16_t f2b(float f) {
    unsigned int u;
    __builtin_memcpy(&u, &f, 4);
    u += 0x7fffu + ((u >> 16) & 1u);
    return (bf16_t)(u >> 16);
}
static __device__ __forceinline__ float sigmoidf_(float x) {
    return 1.0f / (1.0f + __expf(-x));
}
static __device__ __forceinline__ void gload_lds16(const void* g, void* l) {
    __builtin_amdgcn_global_load_lds((const __attribute__((address_space(1))) void*)g,
                                     (__attribute__((address_space(3))) void*)l, 16, 0, 0);
}

// ---------------- prologue kernels ----------------

__global__ void fuse_wb_k(const float* __restrict__ cw, const float* __restrict__ cb,
                          const float* __restrict__ fwm, const float* __restrict__ fbv,
                          float* __restrict__ fw, float* __restrict__ fb) {
    int c = threadIdx.x;
    float a = 0.f, bs = 0.f;
    for (int o = 0; o < C_; o++) {
        float f = fwm[o * C_ + c];
        a += cw[o] * f;
        bs += cb[o] * f;
    }
    fw[c] = a;
    fb[c] = bs + fbv[c];
}

// Transposed bf16 weights WT[(l*6+tp)][m][k]; tp: 0=q 1=k 2=v 3=f 4=wa_even 5=wa_odd.
// q/k/v rows get pre-scaled by ln gamma: W'[k][m] = g[k]*W[k][m]  (LN fold).
__global__ __launch_bounds__(256) void wtrans_k(const float* __restrict__ wq, const float* __restrict__ wk,
                                                const float* __restrict__ wv, const float* __restrict__ wf,
                                                const float* __restrict__ wa, const float* __restrict__ ln_s,
                                                bf16_t* __restrict__ WT) {
    __shared__ float t[32][33];
    int z = blockIdx.z, l = z / 6, tp = z - l * 6;
    const float* src;
    int ld, cmul, coff;
    if (tp < 4) {
        const float* bases[4] = {wq, wk, wv, wf};
        src = bases[tp] + (size_t)l * 65536;
        ld = 256; cmul = 1; coff = 0;
    } else {
        src = wa + (size_t)l * 131072;
        ld = 512; cmul = 2; coff = tp - 4;
    }
    const float* g = ln_s + l * 256;
    bf16_t* dst = WT + ((size_t)l * 6 + tp) * 65536;
    int k0 = blockIdx.y * 32, m0 = blockIdx.x * 32;
    int tx = threadIdx.x & 31, ty = threadIdx.x >> 5;
#pragma unroll
    for (int r = 0; r < 4; ++r) {
        int k = k0 + ty + 8 * r;
        float v = src[(size_t)k * ld + (m0 + tx) * cmul + coff];
        if (tp < 3) v *= g[k];
        t[ty + 8 * r][tx] = v;
    }
    __syncthreads();
#pragma unroll
    for (int r = 0; r < 4; ++r)
        dst[(size_t)(m0 + ty + 8 * r) * 256 + k0 + tx] = f2b(t[tx][ty + 8 * r]);
}

// Per (layer, mat in {q,k,v}, m): csum[m] = sum_k W'[m][k] (from WT),
// bias2[m] = b[m] + sum_k ln_b[k]*W[k][m] (from original fp32 weights).
__global__ __launch_bounds__(256) void colsum_k(const bf16_t* __restrict__ WT,
                                                const float* __restrict__ wq, const float* __restrict__ wk,
                                                const float* __restrict__ wv,
                                                const float* __restrict__ bq, const float* __restrict__ bk,
                                                const float* __restrict__ bv,
                                                const float* __restrict__ ln_b,
                                                float* __restrict__ csum, float* __restrict__ bias2) {
    int m = threadIdx.x, mat = blockIdx.x, l = blockIdx.y;
    const bf16_t* wt = WT + ((size_t)l * 6 + mat) * 65536 + (size_t)m * 256;
    float cs = 0.f;
    for (int k = 0; k < 256; k += 8) {
        s8v u = *(const s8v*)(wt + k);
#pragma unroll
        for (int j = 0; j < 8; ++j) cs += b2f((bf16_t)u[j]);
    }
    const float* worig = (mat == 0 ? wq : mat == 1 ? wk : wv) + (size_t)l * 65536;
    const float* borig = (mat == 0 ? bq : mat == 1 ? bk : bv) + l * 256;
    const float* lb = ln_b + l * 256;
    float bb = 0.f;
    for (int k = 0; k < 256; ++k) bb += lb[k] * worig[(size_t)k * 256 + m];
    int o = (l * 3 + mat) * 256 + m;
    csum[o] = cs;
    bias2[o] = bb + borig[m];
}

// X[b][s][c] = tanh(img_pixel(b,s)*fw[c]+fb[c])  -- (B,S,C) bf16, wave per row.
// Seeds PART[row][0]=(sum,sq), PART[row][1..7]=0  (8 float2 = 64B per row).
__global__ __launch_bounds__(256) void embed_k(const float* __restrict__ img, const float* __restrict__ fw,
                                               const float* __restrict__ fb, bf16_t* __restrict__ X,
                                               float* __restrict__ PART) {
    int wid = threadIdx.x >> 6, lane = threadIdx.x & 63;
    int row = blockIdx.x * 4 + wid;          // b*1024+s
    int b = row >> 10, s = row & 1023;
    float xv = img[(size_t)b * 262144 + (size_t)(s >> 5) * 8192 + (s & 31) * 16];
    f4v fwv = *(const f4v*)(fw + lane * 4);
    f4v fbv = *(const f4v*)(fb + lane * 4);
    s4v o;
    float sum = 0.f, sq = 0.f;
#pragma unroll
    for (int j = 0; j < 4; ++j) {
        float v = tanhf(xv * fwv[j] + fbv[j]);
        float vb = b2f(f2b(v));  // stats on the stored bf16 value
        o[j] = (short)f2b(v);
        sum += vb;
        sq += vb * vb;
    }
    *(s4v*)(X + (size_t)row * 256 + lane * 4) = o;
#pragma unroll
    for (int off = 32; off > 0; off >>= 1) {
        sum += __shfl_xor(sum, off);
        sq += __shfl_xor(sq, off);
    }
    float sb = __shfl(sum, 0), qb = __shfl(sq, 0);
    if (lane < 8) {
        float2 v = (lane == 0) ? make_float2(sb, qb) : make_float2(0.f, 0.f);
        *(float2*)(PART + (size_t)row * 16 + lane * 2) = v;
    }
}

// ---------------- MFMA GEMM (proven tiling: BM=128, BN=64, BK=64) ----------------
// XCD-aware bijective block swizzle: consecutive HW indices round-robin across the 8
// XCDs; remap so each XCD runs all mt tiles of a contiguous set of (s,b) groups ->
// A-tiles are fetched once per XCD then L2-hit, weights become L2-resident.
// MODE 0: QKV stacked (M=768) on RAW x with LN fold (stats from PART[row][0..7]) ->
//         (B,C,S) Q/K/V via LDS-transpose epilogue.
// MODE 1: gate dual: tn2 = sig(acc0+ba[2m])*ta + sig(acc1+ba[2m+1]) -> O0 (B,S,C).
// MODE 2: wf: x = relu(acc+bf)+ta -> O0 (B,S,C), optional fp32 hid; writes per-row
//         partial (sum,sq) of its 64-col slice into partOut[row][mt*2+wcol].
template <int MODE, bool HID>
__global__ __launch_bounds__(256) void mm_k(const bf16_t* Ain,
                                            const bf16_t* __restrict__ W0,
                                            const bf16_t* __restrict__ W1,
                                            const float* __restrict__ bias0,
                                            const float* __restrict__ csP,
                                            const float* __restrict__ PART,
                                            const bf16_t* ta,
                                            bf16_t* O0, bf16_t* O1, bf16_t* O2,
                                            float* __restrict__ hid,
                                            float* __restrict__ partOut) {
    constexpr int LDSZ = (MODE == 0) ? 34816 : 32768;
    constexpr int NX = (MODE == 0) ? 12 : 4;          // grid x extent
    constexpr int NWG = NX * 8 * 32;
    constexpr int CPX = NWG / 8;                      // chunk per XCD
    __shared__ char lds[LDSZ];
    char* XS = lds;             // [128 rows][128B]
    char* WS0 = lds + 16384;    // [64 rows][128B]
    char* WS1 = lds + 24576;    // MODE1 only
    const int tid = threadIdx.x, lane = tid & 63, wid = tid >> 6;
    const int wrow = wid >> 1, wcol = wid & 1;

    // bijective XCD swizzle (NWG % 8 == 0)
    const int id = blockIdx.x + NX * (blockIdx.y + 8 * blockIdx.z);
    const int logical = (id & 7) * CPX + (id >> 3);
    const int mt = logical % NX;
    const int yz = logical / NX;
    const int s0 = (yz & 7) * 128, mt0 = mt * 64, b = yz >> 3;

    if constexpr (MODE == 0) {
        // pre-phase: combine 8 partials per row -> (rs, rs*mu) in LDS (region after WS0)
        float2* stats = (float2*)(lds + 24576);
        if (tid < 128) {
            int sg = b * 1024 + s0 + tid;
            const float* pp = PART + (size_t)sg * 16;
            f4v p0 = *(const f4v*)pp;
            f4v p1 = *(const f4v*)(pp + 4);
            f4v p2 = *(const f4v*)(pp + 8);
            f4v p3 = *(const f4v*)(pp + 12);
            float su = p0[0] + p0[2] + p1[0] + p1[2] + p2[0] + p2[2] + p3[0] + p3[2];
            float qq = p0[1] + p0[3] + p1[1] + p1[3] + p2[1] + p2[3] + p3[1] + p3[3];
            float mu = su * (1.f / 256.f);
            float var = qq * (1.f / 256.f) - mu * mu;
            float rsv = rsqrtf(var + 1e-5f);
            stats[tid] = make_float2(rsv, rsv * mu);
        }
    }

    const int lr8 = lane >> 3;
    const int cb0 = ((lane & 7) << 4) ^ (lr8 << 4);  // pre-swizzled source col byte

    const char* Ag = (const char*)Ain + (((size_t)b * 1024 + s0) * 256) * 2 + cb0;
    const char* Wg0 = (const char*)W0 + ((size_t)mt0 * 256) * 2 + cb0;
    const char* Wg1 = (const char*)W1 + ((size_t)mt0 * 256) * 2 + cb0;

    f4v acc[4][2] = {};
    f4v acc1[4][2] = {};

    for (int kt = 0; kt < 4; ++kt) {
        const char* ga = Ag + kt * 128;
#pragma unroll
        for (int q = 0; q < 4; ++q) {
            int r0 = wid * 32 + q * 8;
            gload_lds16(ga + (size_t)(r0 + lr8) * 512, XS + r0 * 128);
        }
        const char* gw = Wg0 + kt * 128;
#pragma unroll
        for (int p = 0; p < 2; ++p) {
            int r0 = wid * 16 + p * 8;
            gload_lds16(gw + (size_t)(r0 + lr8) * 512, WS0 + r0 * 128);
        }
        if constexpr (MODE == 1) {
            const char* gw1 = Wg1 + kt * 128;
#pragma unroll
            for (int p = 0; p < 2; ++p) {
                int r0 = wid * 16 + p * 8;
                gload_lds16(gw1 + (size_t)(r0 + lr8) * 512, WS1 + r0 * 128);
            }
        }
        __syncthreads();
#pragma unroll
        for (int kk = 0; kk < 2; ++kk) {
            const int cb = kk * 64 + ((lane >> 4) << 4);
            s8v av[4];
#pragma unroll
            for (int mi = 0; mi < 4; ++mi) {
                int r = wrow * 64 + mi * 16 + (lane & 15);
                av[mi] = *(const s8v*)(XS + r * 128 + (cb ^ ((r & 7) << 4)));
            }
            s8v bv[2], bw[2];
#pragma unroll
            for (int ni = 0; ni < 2; ++ni) {
                int m = wcol * 32 + ni * 16 + (lane & 15);
                bv[ni] = *(const s8v*)(WS0 + m * 128 + (cb ^ ((m & 7) << 4)));
                if constexpr (MODE == 1)
                    bw[ni] = *(const s8v*)(WS1 + m * 128 + (cb ^ ((m & 7) << 4)));
            }
#pragma unroll
            for (int mi = 0; mi < 4; ++mi)
#pragma unroll
                for (int ni = 0; ni < 2; ++ni) {
                    acc[mi][ni] = __builtin_amdgcn_mfma_f32_16x16x32_bf16(av[mi], bv[ni], acc[mi][ni], 0, 0, 0);
                    if constexpr (MODE == 1)
                        acc1[mi][ni] = __builtin_amdgcn_mfma_f32_16x16x32_bf16(av[mi], bw[ni], acc1[mi][ni], 0, 0, 0);
                }
        }
        __syncthreads();
    }

    if constexpr (MODE == 0) {
        const int mat = mt0 >> 8, mw = mt0 & 255;
        const float* bs = bias0 + mat * 256 + mw;
        const float* cs = csP + mat * 256 + mw;
        bf16_t* Os = (mat == 0) ? O0 : (mat == 1 ? O1 : O2);
        const float2* stats = (const float2*)(lds + 24576);
        bf16_t* T = (bf16_t*)lds;  // [64][144]
#pragma unroll
        for (int mi = 0; mi < 4; ++mi)
#pragma unroll
            for (int r = 0; r < 4; ++r) {
                int sl = wrow * 64 + mi * 16 + (lane >> 4) * 4 + r;
                float2 st = stats[sl];
                float a = st.x, cc = st.y;
#pragma unroll
                for (int ni = 0; ni < 2; ++ni) {
                    int ml = wcol * 32 + ni * 16 + (lane & 15);
                    float v = sigmoidf_(a * acc[mi][ni][r] - cc * cs[ml] + bs[ml]);
                    T[ml * 144 + sl] = f2b(v);
                }
            }
        __syncthreads();
        int m = tid >> 2, c0s = (tid & 3) * 32;
        bf16_t* dst = Os + ((size_t)(b * 256 + mw + m)) * 1024 + s0 + c0s;
#pragma unroll
        for (int j = 0; j < 4; ++j)
            *(s8v*)(dst + j * 8) = *(const s8v*)(T + m * 144 + c0s + j * 8);
    } else if constexpr (MODE == 1) {
#pragma unroll
        for (int mi = 0; mi < 4; ++mi)
#pragma unroll
            for (int ni = 0; ni < 2; ++ni) {
                int ml = mt0 + wcol * 32 + ni * 16 + (lane & 15);
#pragma unroll
                for (int r = 0; r < 4; ++r) {
                    int sg = b * 1024 + s0 + wrow * 64 + mi * 16 + (lane >> 4) * 4 + r;
                    size_t idx = (size_t)sg * 256 + ml;
                    float v = sigmoidf_(acc[mi][ni][r] + bias0[2 * ml]) * b2f(ta[idx]) +
                              sigmoidf_(acc1[mi][ni][r] + bias0[2 * ml + 1]);
                    O0[idx] = f2b(v);
                }
            }
    } else {
#pragma unroll
        for (int mi = 0; mi < 4; ++mi)
#pragma unroll
            for (int r = 0; r < 4; ++r) {
                int sg = b * 1024 + s0 + wrow * 64 + mi * 16 + (lane >> 4) * 4 + r;
                float vv[2];
#pragma unroll
                for (int ni = 0; ni < 2; ++ni) {
                    int ml = mt0 + wcol * 32 + ni * 16 + (lane & 15);
                    size_t idx = (size_t)sg * 256 + ml;
                    float v = fmaxf(acc[mi][ni][r] + bias0[ml], 0.f) + b2f(ta[idx]);
                    O0[idx] = f2b(v);
                    if constexpr (HID) hid[idx] = v;
                    vv[ni] = v;
                }
                // per-row partial over this wave's 32 cols -> indexed slot (no atomics)
                float ps = vv[0] + vv[1];
                float pq = vv[0] * vv[0] + vv[1] * vv[1];
                ps += __shfl_xor(ps, 1); pq += __shfl_xor(pq, 1);
                ps += __shfl_xor(ps, 2); pq += __shfl_xor(pq, 2);
                ps += __shfl_xor(ps, 4); pq += __shfl_xor(pq, 4);
                ps += __shfl_xor(ps, 8); pq += __shfl_xor(pq, 8);
                if ((lane & 15) == 0)
                    *(float2*)(partOut + (size_t)sg * 16 + (mt * 2 + wcol) * 2) =
                        make_float2(ps, pq);
            }
    }
}

// ---------------- attention (MFMA, barrier-free, fragments direct from global) ----------------
// One wave per (b,c). Q,K,V,A all (B,C,S) bf16. A = attention output (not accumulated).
__global__ __launch_bounds__(256) void attn_k(const bf16_t* __restrict__ Q, const bf16_t* __restrict__ K,
                                              const bf16_t* __restrict__ V, bf16_t* __restrict__ A) {
    __shared__ char Lds[35840];
    const int w = threadIdx.x >> 6, lane = threadIdx.x & 63;
    char* P = Lds + w * 8960;
    const int gw = blockIdx.x * 4 + w;
    const int b = gw >> 8, c = gw & 255;
    const size_t base = ((size_t)b * 256 + c) * 1024;
    constexpr int VT = 0, S1 = 2560, S2 = 5120, KQ = 6400;
    const f4v zf = {0.f, 0.f, 0.f, 0.f};
    const int frow = lane & 15, fhalf = lane >> 4;
    const int fbyte = fhalf * 16;
    const bf16_t* Qg = Q + base;
    const bf16_t* Kg = K + base;
    const bf16_t* Vg = V + base;

    // direct global fragment loads (rows are 32 bf16 = 64B, contiguous)
    s8v aq0 = *(const s8v*)(Qg + frow * 32 + fhalf * 8);
    s8v aq1 = *(const s8v*)(Qg + (16 + frow) * 32 + fhalf * 8);
    s8v bk0 = *(const s8v*)(Kg + frow * 32 + fhalf * 8);
    s8v bk1 = *(const s8v*)(Kg + (16 + frow) * 32 + fhalf * 8);
    // pooled fragments in registers (rows clamped; rows>=8 are discarded garbage)
    float accq[8], acck[8];
#pragma unroll
    for (int j = 0; j < 8; ++j) { accq[j] = 0.f; acck[j] = 0.f; }
#pragma unroll
    for (int pp = 0; pp < 4; ++pp) {
        int rr = 4 * frow + pp;
        if (rr > 31) rr = 31;
        s8v uq = *(const s8v*)(Qg + rr * 32 + fhalf * 8);
        s8v uk = *(const s8v*)(Kg + rr * 32 + fhalf * 8);
#pragma unroll
        for (int j = 0; j < 8; ++j) {
            accq[j] += b2f((bf16_t)uq[j]);
            acck[j] += b2f((bf16_t)uk[j]);
        }
    }
    s8v aqp, bkp;
#pragma unroll
    for (int j = 0; j < 8; ++j) {
        aqp[j] = (short)f2b(accq[j] * 0.25f);
        bkp[j] = (short)f2b(acck[j] * 0.25f);
    }
    // V load + LDS transpose staging
    {
        s8v v0 = *(const s8v*)(Vg + lane * 16);
        s8v v1 = *(const s8v*)(Vg + lane * 16 + 8);
        int pw = lane >> 1, ph0 = (lane & 1) * 16;
#pragma unroll
        for (int j = 0; j < 8; ++j) {
            *(bf16_t*)(P + VT + (ph0 + j) * 80 + pw * 2) = (bf16_t)(unsigned short)v0[j];
            *(bf16_t*)(P + VT + (ph0 + 8 + j) * 80 + pw * 2) = (bf16_t)(unsigned short)v1[j];
        }
    }
    // zero-fill pad regions (before the partial writes below; in-order LDS pipe)
    if (lane < 32) {
#pragma unroll
        for (int q = 0; q < 4; ++q) *(f4v*)(P + S1 + lane * 80 + q * 16) = zf;   // s1 rows, full 64B
#pragma unroll
        for (int q = 0; q < 3; ++q) *(f4v*)(P + KQ + lane * 80 + 16 + q * 16) = zf;  // kqvT k-pad
    } else if (lane < 40) {
#pragma unroll
        for (int q = 0; q < 4; ++q) *(f4v*)(P + S2 + (lane - 24) * 80 + q * 16) = zf;  // s2 rows 8..15
    }

    // stage 1&2 MFMAs (register inputs only)
    f4v s1a = __builtin_amdgcn_mfma_f32_16x16x32_bf16(aq0, bkp, zf, 0, 0, 0);
    f4v s1b = __builtin_amdgcn_mfma_f32_16x16x32_bf16(aq1, bkp, zf, 0, 0, 0);
    f4v s2a = __builtin_amdgcn_mfma_f32_16x16x32_bf16(aqp, bk0, zf, 0, 0, 0);
    f4v s2b = __builtin_amdgcn_mfma_f32_16x16x32_bf16(aqp, bk1, zf, 0, 0, 0);

    const float dsc = 0.0625f;  // 1/sqrt(256)
    // softmax s1 (rows 32, valid cols j<8) -> S1 bytes 0..15 of each row
    {
        int j = lane & 15;
#pragma unroll
        for (int t = 0; t < 2; ++t) {
            f4v av = t ? s1b : s1a;
#pragma unroll
            for (int r = 0; r < 4; ++r) {
                float x = av[r] * dsc;
                float m = x;
                m = fmaxf(m, __shfl_xor(m, 1));
                m = fmaxf(m, __shfl_xor(m, 2));
                m = fmaxf(m, __shfl_xor(m, 4));
                float e2 = __expf(x - m);
                float s = e2;
                s += __shfl_xor(s, 1);
                s += __shfl_xor(s, 2);
                s += __shfl_xor(s, 4);
                float p = e2 / s;
                if (j < 8) {
                    int row = t * 16 + fhalf * 4 + r;
                    *(bf16_t*)(P + S1 + row * 80 + j * 2) = f2b(p);
                }
            }
        }
    }
    // softmax s2 (valid rows i2<8, 32 cols across two tiles) -> S2 rows 0..7
#pragma unroll
    for (int r = 0; r < 4; ++r) {
        float xa = s2a[r] * dsc, xb = s2b[r] * dsc;
        float m = fmaxf(xa, xb);
        m = fmaxf(m, __shfl_xor(m, 1));
        m = fmaxf(m, __shfl_xor(m, 2));
        m = fmaxf(m, __shfl_xor(m, 4));
        m = fmaxf(m, __shfl_xor(m, 8));
        float ea = __expf(xa - m), eb = __expf(xb - m);
        float s = ea + eb;
        s += __shfl_xor(s, 1);
        s += __shfl_xor(s, 2);
        s += __shfl_xor(s, 4);
        s += __shfl_xor(s, 8);
        float inv = 1.f / s;
        if (lane < 32) {
            int row = fhalf * 4 + r;
            *(bf16_t*)(P + S2 + row * 80 + frow * 2) = f2b(ea * inv);
            *(bf16_t*)(P + S2 + row * 80 + (16 + frow) * 2) = f2b(eb * inv);
        }
    }
    __builtin_amdgcn_wave_barrier();
    // stage 3: kqv = s2·V -> write kqv^T into KQ (rows=ph, cols=i2)
    {
        s8v as2 = *(const s8v*)(P + S2 + frow * 80 + fbyte);
        s8v bv0 = *(const s8v*)(P + VT + frow * 80 + fbyte);
        s8v bv1 = *(const s8v*)(P + VT + (16 + frow) * 80 + fbyte);
        f4v k3a = __builtin_amdgcn_mfma_f32_16x16x32_bf16(as2, bv0, zf, 0, 0, 0);
        f4v k3b = __builtin_amdgcn_mfma_f32_16x16x32_bf16(as2, bv1, zf, 0, 0, 0);
        if (lane < 32) {
#pragma unroll
            for (int r = 0; r < 4; ++r) {
                int i2 = fhalf * 4 + r;
                *(bf16_t*)(P + KQ + frow * 80 + i2 * 2) = f2b(k3a[r]);
                *(bf16_t*)(P + KQ + (16 + frow) * 80 + i2 * 2) = f2b(k3b[r]);
            }
        }
    }
    __builtin_amdgcn_wave_barrier();
    // stage 4: out = s1·kqv  (k=8 zero-padded to 32)
    {
        s8v a40 = *(const s8v*)(P + S1 + frow * 80 + fbyte);
        s8v a41 = *(const s8v*)(P + S1 + (16 + frow) * 80 + fbyte);
        s8v b40 = *(const s8v*)(P + KQ + frow * 80 + fbyte);
        s8v b41 = *(const s8v*)(P + KQ + (16 + frow) * 80 + fbyte);
        f4v o00 = __builtin_amdgcn_mfma_f32_16x16x32_bf16(a40, b40, zf, 0, 0, 0);
        f4v o01 = __builtin_amdgcn_mfma_f32_16x16x32_bf16(a40, b41, zf, 0, 0, 0);
        f4v o10 = __builtin_amdgcn_mfma_f32_16x16x32_bf16(a41, b40, zf, 0, 0, 0);
        f4v o11 = __builtin_amdgcn_mfma_f32_16x16x32_bf16(a41, b41, zf, 0, 0, 0);
#pragma unroll
        for (int r = 0; r < 4; ++r) {
            int r0 = fhalf * 4 + r;
            *(bf16_t*)(P + VT + r0 * 80 + frow * 2) = f2b(o00[r]);
            *(bf16_t*)(P + VT + r0 * 80 + (16 + frow) * 2) = f2b(o01[r]);
            *(bf16_t*)(P + VT + (16 + r0) * 80 + frow * 2) = f2b(o10[r]);
            *(bf16_t*)(P + VT + (16 + r0) * 80 + (16 + frow) * 2) = f2b(o11[r]);
        }
    }
    __builtin_amdgcn_wave_barrier();
    {
        int i = lane >> 1, hh = (lane & 1) * 32;
        s8v r0 = *(const s8v*)(P + VT + i * 80 + hh);
        s8v r1 = *(const s8v*)(P + VT + i * 80 + hh + 16);
        *(s8v*)(A + base + lane * 16) = r0;
        *(s8v*)(A + base + lane * 16 + 8) = r1;
    }
}

// ta = X + A^T : A (B,C,S) -> add into X (B,S,C); optional fp32 att snapshot
template <bool SNAP>
__global__ __launch_bounds__(256) void add_tr_k(const bf16_t* __restrict__ Aa, bf16_t* X,
                                                float* __restrict__ att) {
    __shared__ float T[32][33];
    int b = blockIdx.z, c0 = blockIdx.y * 32, s0 = blockIdx.x * 32;
    int tx = threadIdx.x & 31, ty = threadIdx.x >> 5;
#pragma unroll
    for (int r = 0; r < 4; ++r)
        T[ty + 8 * r][tx] = b2f(Aa[((size_t)(b * 256 + c0 + ty + 8 * r)) * 1024 + s0 + tx]);
    __syncthreads();
#pragma unroll
    for (int r = 0; r < 4; ++r) {
        int s = s0 + ty + 8 * r;
        size_t idx = ((size_t)(b * 1024 + s)) * 256 + c0 + tx;
        float v = b2f(X[idx]) + T[tx][ty + 8 * r];
        X[idx] = f2b(v);
        if constexpr (SNAP) att[idx] = v;
    }
}

// ---------------- launch ----------------

extern "C" void kernel_launch(void* const* d_in, const int* in_sizes, int n_in,
                              void* d_out, int out_size, void* d_ws, size_t ws_size,
                              hipStream_t stream) {
    const float* image  = (const float*)d_in[0];
    const float* conv_w = (const float*)d_in[1];
    const float* conv_b = (const float*)d_in[2];
    const float* feat_w = (const float*)d_in[3];
    const float* feat_b = (const float*)d_in[4];
    const float* ln_s   = (const float*)d_in[5];
    const float* ln_b   = (const float*)d_in[6];
    const float* wq     = (const float*)d_in[7];
    const float* bq     = (const float*)d_in[8];
    const float* wk     = (const float*)d_in[9];
    const float* bk     = (const float*)d_in[10];
    const float* wv     = (const float*)d_in[11];
    const float* bv     = (const float*)d_in[12];
    const float* wf     = (const float*)d_in[13];
    const float* bfv    = (const float*)d_in[14];
    const float* wa     = (const float*)d_in[15];
    const float* ba     = (const float*)d_in[16];
    float* out = (float*)d_out;

    char* p = (char*)d_ws;
    const size_t MB16 = (size_t)B_ * S_ * C_ * sizeof(bf16_t);  // 16777216
    float* fw    = (float*)p;  p += 1024;
    float* fb    = (float*)p;  p += 1024;
    float* PART  = (float*)p;  p += 2097152;   // 32768 rows x 8 float2 (64B/row)
    float* csum  = (float*)p;  p += 24576;
    float* bias2 = (float*)p;  p += 24576;
    bf16_t* WT = (bf16_t*)p;   p += (size_t)48 * 65536 * 2;
    bf16_t* X  = (bf16_t*)p;   p += MB16;
    bf16_t* T1 = (bf16_t*)p;   p += MB16;  // attn-delta
    bf16_t* T2 = (bf16_t*)p;   p += MB16;  // tn2
    bf16_t* Qb = (bf16_t*)p;   p += MB16;
    bf16_t* Kb = (bf16_t*)p;   p += MB16;
    bf16_t* Vb = (bf16_t*)p;   p += MB16;
    size_t needed = (size_t)(p - (char*)d_ws);
    if (ws_size < needed) Vb = (bf16_t*)d_out;  // out slot0 only written at the very end

    fuse_wb_k<<<1, 256, 0, stream>>>(conv_w, conv_b, feat_w, feat_b, fw, fb);
    wtrans_k<<<dim3(8, 8, 48), 256, 0, stream>>>(wq, wk, wv, wf, wa, ln_s, WT);
    colsum_k<<<dim3(3, 8), 256, 0, stream>>>(WT, wq, wk, wv, bq, bk, bv, ln_b, csum, bias2);
    embed_k<<<8192, 256, 0, stream>>>(image, fw, fb, X, PART);

    const size_t slot = (size_t)B_ * S_ * C_;

    for (int l = 0; l < L_; ++l) {
        const bf16_t* WTl = WT + (size_t)l * 6 * 65536;
        int snap = (l == 2) ? 0 : (l == 4) ? 1 : (l == 6) ? 2 : -1;

        mm_k<0, false><<<dim3(12, 8, 32), 256, 0, stream>>>(
            X, WTl, nullptr, bias2 + l * 768, csum + l * 768, PART, nullptr,
            Qb, Kb, Vb, nullptr, nullptr);
        attn_k<<<2048, 256, 0, stream>>>(Qb, Kb, Vb, T1);
        if (snap >= 0)
            add_tr_k<true><<<dim3(32, 8, 32), 256, 0, stream>>>(T1, X, out + (size_t)(4 + snap) * slot);
        else
            add_tr_k<false><<<dim3(32, 8, 32), 256, 0, stream>>>(T1, X, nullptr);
        // X is now ta
        mm_k<1, false><<<dim3(4, 8, 32), 256, 0, stream>>>(
            X, WTl + 4 * 65536, WTl + 5 * 65536, ba + l * 512, nullptr, nullptr, X,
            T2, nullptr, nullptr, nullptr, nullptr);
        float* hid = (snap >= 0) ? out + (size_t)(1 + snap) * slot : (l == 7 ? out : nullptr);
        if (hid)
            mm_k<2, true><<<dim3(4, 8, 32), 256, 0, stream>>>(
                T2, WTl + 3 * 65536, nullptr, bfv + l * 256, nullptr, nullptr, X,
                X, nullptr, nullptr, hid, PART);
        else
            mm_k<2, false><<<dim3(4, 8, 32), 256, 0, stream>>>(
                T2, WTl + 3 * 65536, nullptr, bfv + l * 256, nullptr, nullptr, X,
                X, nullptr, nullptr, nullptr, PART);
    }
}

// Round 10
// 960.219 us; speedup vs baseline: 1.3279x; 1.0317x over previous
//
#include <hip/hip_runtime.h>
#include <hip/hip_bf16.h>
#include <cstdint>
#include <cstddef>

#define B_ 32
#define C_ 256
#define S_ 1024
#define L_ 8

typedef unsigned short bf16_t;
typedef __attribute__((ext_vector_type(8))) short s8v;   // 8 bf16 (16B)
typedef __attribute__((ext_vector_type(4))) short s4v;   // 4 bf16 (8B)
typedef __attribute__((ext_vector_type(4))) float f4v;

static __device__ __forceinline__ float b2f(bf16_t v) {
    unsigned int u = ((unsigned int)v) << 16;
    float f;
    __builtin_memcpy(&f, &u, 4);
    return f;
}
static __device__ __forceinline__ bf16_t f2b(float f) {
    unsigned int u;
    __builtin_memcpy(&u, &f, 4);
    u += 0x7fffu + ((u >> 16) & 1u);
    return (bf16_t)(u >> 16);
}
static __device__ __forceinline__ float sigmoidf_(float x) {
    return 1.0f / (1.0f + __expf(-x));
}
static __device__ __forceinline__ void gload_lds16(const void* g, void* l) {
    __builtin_amdgcn_global_load_lds((const __attribute__((address_space(1))) void*)g,
                                     (__attribute__((address_space(3))) void*)l, 16, 0, 0);
}

// ---------------- prologue kernels ----------------

__global__ void fuse_wb_k(const float* __restrict__ cw, const float* __restrict__ cb,
                          const float* __restrict__ fwm, const float* __restrict__ fbv,
                          float* __restrict__ fw, float* __restrict__ fb) {
    int c = threadIdx.x;
    float a = 0.f, bs = 0.f;
    for (int o = 0; o < C_; o++) {
        float f = fwm[o * C_ + c];
        a += cw[o] * f;
        bs += cb[o] * f;
    }
    fw[c] = a;
    fb[c] = bs + fbv[c];
}

// Transposed bf16 weights WT[(l*6+tp)][m][k]; tp: 0=q 1=k 2=v 3=f 4=wa_even 5=wa_odd.
// q/k/v rows get pre-scaled by ln gamma: W'[k][m] = g[k]*W[k][m]  (LN fold).
__global__ __launch_bounds__(256) void wtrans_k(const float* __restrict__ wq, const float* __restrict__ wk,
                                                const float* __restrict__ wv, const float* __restrict__ wf,
                                                const float* __restrict__ wa, const float* __restrict__ ln_s,
                                                bf16_t* __restrict__ WT) {
    __shared__ float t[32][33];
    int z = blockIdx.z, l = z / 6, tp = z - l * 6;
    const float* src;
    int ld, cmul, coff;
    if (tp < 4) {
        const float* bases[4] = {wq, wk, wv, wf};
        src = bases[tp] + (size_t)l * 65536;
        ld = 256; cmul = 1; coff = 0;
    } else {
        src = wa + (size_t)l * 131072;
        ld = 512; cmul = 2; coff = tp - 4;
    }
    const float* g = ln_s + l * 256;
    bf16_t* dst = WT + ((size_t)l * 6 + tp) * 65536;
    int k0 = blockIdx.y * 32, m0 = blockIdx.x * 32;
    int tx = threadIdx.x & 31, ty = threadIdx.x >> 5;
#pragma unroll
    for (int r = 0; r < 4; ++r) {
        int k = k0 + ty + 8 * r;
        float v = src[(size_t)k * ld + (m0 + tx) * cmul + coff];
        if (tp < 3) v *= g[k];
        t[ty + 8 * r][tx] = v;
    }
    __syncthreads();
#pragma unroll
    for (int r = 0; r < 4; ++r)
        dst[(size_t)(m0 + ty + 8 * r) * 256 + k0 + tx] = f2b(t[tx][ty + 8 * r]);
}

// Per (layer, mat in {q,k,v}, m): csum[m] = sum_k W'[m][k] (from WT),
// bias2[m] = b[m] + sum_k ln_b[k]*W[k][m] (from original fp32 weights).
__global__ __launch_bounds__(256) void colsum_k(const bf16_t* __restrict__ WT,
                                                const float* __restrict__ wq, const float* __restrict__ wk,
                                                const float* __restrict__ wv,
                                                const float* __restrict__ bq, const float* __restrict__ bk,
                                                const float* __restrict__ bv,
                                                const float* __restrict__ ln_b,
                                                float* __restrict__ csum, float* __restrict__ bias2) {
    int m = threadIdx.x, mat = blockIdx.x, l = blockIdx.y;
    const bf16_t* wt = WT + ((size_t)l * 6 + mat) * 65536 + (size_t)m * 256;
    float cs = 0.f;
    for (int k = 0; k < 256; k += 8) {
        s8v u = *(const s8v*)(wt + k);
#pragma unroll
        for (int j = 0; j < 8; ++j) cs += b2f((bf16_t)u[j]);
    }
    const float* worig = (mat == 0 ? wq : mat == 1 ? wk : wv) + (size_t)l * 65536;
    const float* borig = (mat == 0 ? bq : mat == 1 ? bk : bv) + l * 256;
    const float* lb = ln_b + l * 256;
    float bb = 0.f;
    for (int k = 0; k < 256; ++k) bb += lb[k] * worig[(size_t)k * 256 + m];
    int o = (l * 3 + mat) * 256 + m;
    csum[o] = cs;
    bias2[o] = bb + borig[m];
}

// X[b][s][c] = tanh(img_pixel(b,s)*fw[c]+fb[c])  -- (B,S,C) bf16, wave per row.
// Seeds PART[row][0]=(sum,sq), PART[row][1..7]=0. XCD swizzle: XCD x -> batches 4x..4x+3.
__global__ __launch_bounds__(256) void embed_k(const float* __restrict__ img, const float* __restrict__ fw,
                                               const float* __restrict__ fb, bf16_t* __restrict__ X,
                                               float* __restrict__ PART) {
    int wid = threadIdx.x >> 6, lane = threadIdx.x & 63;
    int id = blockIdx.x;                      // 8192 blocks
    int logical = (id & 7) * 1024 + (id >> 3);
    int row = logical * 4 + wid;              // b*1024+s
    int b = row >> 10, s = row & 1023;
    float xv = img[(size_t)b * 262144 + (size_t)(s >> 5) * 8192 + (s & 31) * 16];
    f4v fwv = *(const f4v*)(fw + lane * 4);
    f4v fbv = *(const f4v*)(fb + lane * 4);
    s4v o;
    float sum = 0.f, sq = 0.f;
#pragma unroll
    for (int j = 0; j < 4; ++j) {
        float v = tanhf(xv * fwv[j] + fbv[j]);
        float vb = b2f(f2b(v));  // stats on the stored bf16 value
        o[j] = (short)f2b(v);
        sum += vb;
        sq += vb * vb;
    }
    *(s4v*)(X + (size_t)row * 256 + lane * 4) = o;
#pragma unroll
    for (int off = 32; off > 0; off >>= 1) {
        sum += __shfl_xor(sum, off);
        sq += __shfl_xor(sq, off);
    }
    float sb = __shfl(sum, 0), qb = __shfl(sq, 0);
    if (lane < 8) {
        float2 v = (lane == 0) ? make_float2(sb, qb) : make_float2(0.f, 0.f);
        *(float2*)(PART + (size_t)row * 16 + lane * 2) = v;
    }
}

// ---------------- MFMA GEMM (proven tiling: BM=128, BN=64, BK=64) ----------------
// XCD-aware bijective block swizzle; all kernels share XCD x <-> batches 4x..4x+3 affinity.
// MODE 0: QKV stacked (M=768) on RAW x with LN fold (stats from PART[row][0..7]) ->
//         (B,C,S) Q/K/V via LDS-transpose epilogue.
// MODE 1: gate dual: tn2 = sig(acc0+ba[2m])*ta + sig(acc1+ba[2m+1]) -> O0 (B,S,C).
// MODE 2: wf: x = relu(acc+bf)+ta -> O0 (B,S,C), optional fp32 hid; writes per-row
//         partial (sum,sq) of its 64-col slice into partOut[row][mt*2+wcol].
template <int MODE, bool HID>
__global__ __launch_bounds__(256) void mm_k(const bf16_t* Ain,
                                            const bf16_t* __restrict__ W0,
                                            const bf16_t* __restrict__ W1,
                                            const float* __restrict__ bias0,
                                            const float* __restrict__ csP,
                                            const float* __restrict__ PART,
                                            const bf16_t* ta,
                                            bf16_t* O0, bf16_t* O1, bf16_t* O2,
                                            float* __restrict__ hid,
                                            float* __restrict__ partOut) {
    constexpr int LDSZ = (MODE == 0) ? 34816 : 32768;
    constexpr int NX = (MODE == 0) ? 12 : 4;          // grid x extent
    constexpr int NWG = NX * 8 * 32;
    constexpr int CPX = NWG / 8;                      // chunk per XCD
    __shared__ char lds[LDSZ];
    char* XS = lds;             // [128 rows][128B]
    char* WS0 = lds + 16384;    // [64 rows][128B]
    char* WS1 = lds + 24576;    // MODE1 only
    const int tid = threadIdx.x, lane = tid & 63, wid = tid >> 6;
    const int wrow = wid >> 1, wcol = wid & 1;

    // bijective XCD swizzle (NWG % 8 == 0)
    const int id = blockIdx.x + NX * (blockIdx.y + 8 * blockIdx.z);
    const int logical = (id & 7) * CPX + (id >> 3);
    const int mt = logical % NX;
    const int yz = logical / NX;
    const int s0 = (yz & 7) * 128, mt0 = mt * 64, b = yz >> 3;

    if constexpr (MODE == 0) {
        // pre-phase: combine 8 partials per row -> (rs, rs*mu) in LDS (region after WS0)
        float2* stats = (float2*)(lds + 24576);
        if (tid < 128) {
            int sg = b * 1024 + s0 + tid;
            const float* pp = PART + (size_t)sg * 16;
            f4v p0 = *(const f4v*)pp;
            f4v p1 = *(const f4v*)(pp + 4);
            f4v p2 = *(const f4v*)(pp + 8);
            f4v p3 = *(const f4v*)(pp + 12);
            float su = p0[0] + p0[2] + p1[0] + p1[2] + p2[0] + p2[2] + p3[0] + p3[2];
            float qq = p0[1] + p0[3] + p1[1] + p1[3] + p2[1] + p2[3] + p3[1] + p3[3];
            float mu = su * (1.f / 256.f);
            float var = qq * (1.f / 256.f) - mu * mu;
            float rsv = rsqrtf(var + 1e-5f);
            stats[tid] = make_float2(rsv, rsv * mu);
        }
    }

    const int lr8 = lane >> 3;
    const int cb0 = ((lane & 7) << 4) ^ (lr8 << 4);  // pre-swizzled source col byte

    const char* Ag = (const char*)Ain + (((size_t)b * 1024 + s0) * 256) * 2 + cb0;
    const char* Wg0 = (const char*)W0 + ((size_t)mt0 * 256) * 2 + cb0;
    const char* Wg1 = (const char*)W1 + ((size_t)mt0 * 256) * 2 + cb0;

    f4v acc[4][2] = {};
    f4v acc1[4][2] = {};

    for (int kt = 0; kt < 4; ++kt) {
        const char* ga = Ag + kt * 128;
#pragma unroll
        for (int q = 0; q < 4; ++q) {
            int r0 = wid * 32 + q * 8;
            gload_lds16(ga + (size_t)(r0 + lr8) * 512, XS + r0 * 128);
        }
        const char* gw = Wg0 + kt * 128;
#pragma unroll
        for (int p = 0; p < 2; ++p) {
            int r0 = wid * 16 + p * 8;
            gload_lds16(gw + (size_t)(r0 + lr8) * 512, WS0 + r0 * 128);
        }
        if constexpr (MODE == 1) {
            const char* gw1 = Wg1 + kt * 128;
#pragma unroll
            for (int p = 0; p < 2; ++p) {
                int r0 = wid * 16 + p * 8;
                gload_lds16(gw1 + (size_t)(r0 + lr8) * 512, WS1 + r0 * 128);
            }
        }
        __syncthreads();
#pragma unroll
        for (int kk = 0; kk < 2; ++kk) {
            const int cb = kk * 64 + ((lane >> 4) << 4);
            s8v av[4];
#pragma unroll
            for (int mi = 0; mi < 4; ++mi) {
                int r = wrow * 64 + mi * 16 + (lane & 15);
                av[mi] = *(const s8v*)(XS + r * 128 + (cb ^ ((r & 7) << 4)));
            }
            s8v bv[2], bw[2];
#pragma unroll
            for (int ni = 0; ni < 2; ++ni) {
                int m = wcol * 32 + ni * 16 + (lane & 15);
                bv[ni] = *(const s8v*)(WS0 + m * 128 + (cb ^ ((m & 7) << 4)));
                if constexpr (MODE == 1)
                    bw[ni] = *(const s8v*)(WS1 + m * 128 + (cb ^ ((m & 7) << 4)));
            }
#pragma unroll
            for (int mi = 0; mi < 4; ++mi)
#pragma unroll
                for (int ni = 0; ni < 2; ++ni) {
                    acc[mi][ni] = __builtin_amdgcn_mfma_f32_16x16x32_bf16(av[mi], bv[ni], acc[mi][ni], 0, 0, 0);
                    if constexpr (MODE == 1)
                        acc1[mi][ni] = __builtin_amdgcn_mfma_f32_16x16x32_bf16(av[mi], bw[ni], acc1[mi][ni], 0, 0, 0);
                }
        }
        __syncthreads();
    }

    if constexpr (MODE == 0) {
        const int mat = mt0 >> 8, mw = mt0 & 255;
        const float* bs = bias0 + mat * 256 + mw;
        const float* cs = csP + mat * 256 + mw;
        bf16_t* Os = (mat == 0) ? O0 : (mat == 1 ? O1 : O2);
        const float2* stats = (const float2*)(lds + 24576);
        bf16_t* T = (bf16_t*)lds;  // [64][144]
#pragma unroll
        for (int mi = 0; mi < 4; ++mi)
#pragma unroll
            for (int r = 0; r < 4; ++r) {
                int sl = wrow * 64 + mi * 16 + (lane >> 4) * 4 + r;
                float2 st = stats[sl];
                float a = st.x, cc = st.y;
#pragma unroll
                for (int ni = 0; ni < 2; ++ni) {
                    int ml = wcol * 32 + ni * 16 + (lane & 15);
                    float v = sigmoidf_(a * acc[mi][ni][r] - cc * cs[ml] + bs[ml]);
                    T[ml * 144 + sl] = f2b(v);
                }
            }
        __syncthreads();
        int m = tid >> 2, c0s = (tid & 3) * 32;
        bf16_t* dst = Os + ((size_t)(b * 256 + mw + m)) * 1024 + s0 + c0s;
#pragma unroll
        for (int j = 0; j < 4; ++j)
            *(s8v*)(dst + j * 8) = *(const s8v*)(T + m * 144 + c0s + j * 8);
    } else if constexpr (MODE == 1) {
#pragma unroll
        for (int mi = 0; mi < 4; ++mi)
#pragma unroll
            for (int ni = 0; ni < 2; ++ni) {
                int ml = mt0 + wcol * 32 + ni * 16 + (lane & 15);
#pragma unroll
                for (int r = 0; r < 4; ++r) {
                    int sg = b * 1024 + s0 + wrow * 64 + mi * 16 + (lane >> 4) * 4 + r;
                    size_t idx = (size_t)sg * 256 + ml;
                    float v = sigmoidf_(acc[mi][ni][r] + bias0[2 * ml]) * b2f(ta[idx]) +
                              sigmoidf_(acc1[mi][ni][r] + bias0[2 * ml + 1]);
                    O0[idx] = f2b(v);
                }
            }
    } else {
#pragma unroll
        for (int mi = 0; mi < 4; ++mi)
#pragma unroll
            for (int r = 0; r < 4; ++r) {
                int sg = b * 1024 + s0 + wrow * 64 + mi * 16 + (lane >> 4) * 4 + r;
                float vv[2];
#pragma unroll
                for (int ni = 0; ni < 2; ++ni) {
                    int ml = mt0 + wcol * 32 + ni * 16 + (lane & 15);
                    size_t idx = (size_t)sg * 256 + ml;
                    float v = fmaxf(acc[mi][ni][r] + bias0[ml], 0.f) + b2f(ta[idx]);
                    O0[idx] = f2b(v);
                    if constexpr (HID) hid[idx] = v;
                    vv[ni] = v;
                }
                // per-row partial over this wave's 32 cols -> indexed slot (no atomics)
                float ps = vv[0] + vv[1];
                float pq = vv[0] * vv[0] + vv[1] * vv[1];
                ps += __shfl_xor(ps, 1); pq += __shfl_xor(pq, 1);
                ps += __shfl_xor(ps, 2); pq += __shfl_xor(pq, 2);
                ps += __shfl_xor(ps, 4); pq += __shfl_xor(pq, 4);
                ps += __shfl_xor(ps, 8); pq += __shfl_xor(pq, 8);
                if ((lane & 15) == 0)
                    *(float2*)(partOut + (size_t)sg * 16 + (mt * 2 + wcol) * 2) =
                        make_float2(ps, pq);
            }
    }
}

// ---------------- attention (MFMA, barrier-free, fragments direct from global) ----------------
// One wave per (b,c); XCD swizzle keeps batch affinity with producer mm_k<0>.
__global__ __launch_bounds__(256) void attn_k(const bf16_t* __restrict__ Q, const bf16_t* __restrict__ K,
                                              const bf16_t* __restrict__ V, bf16_t* __restrict__ A) {
    __shared__ char Lds[35840];
    const int w = threadIdx.x >> 6, lane = threadIdx.x & 63;
    char* P = Lds + w * 8960;
    const int id = blockIdx.x;                     // 2048 blocks
    const int logical = (id & 7) * 256 + (id >> 3);
    const int gw = logical * 4 + w;
    const int b = gw >> 8, c = gw & 255;
    const size_t base = ((size_t)b * 256 + c) * 1024;
    constexpr int VT = 0, S1 = 2560, S2 = 5120, KQ = 6400;
    const f4v zf = {0.f, 0.f, 0.f, 0.f};
    const int frow = lane & 15, fhalf = lane >> 4;
    const int fbyte = fhalf * 16;
    const bf16_t* Qg = Q + base;
    const bf16_t* Kg = K + base;
    const bf16_t* Vg = V + base;

    // direct global fragment loads (rows are 32 bf16 = 64B, contiguous)
    s8v aq0 = *(const s8v*)(Qg + frow * 32 + fhalf * 8);
    s8v aq1 = *(const s8v*)(Qg + (16 + frow) * 32 + fhalf * 8);
    s8v bk0 = *(const s8v*)(Kg + frow * 32 + fhalf * 8);
    s8v bk1 = *(const s8v*)(Kg + (16 + frow) * 32 + fhalf * 8);
    // pooled fragments in registers (rows clamped; rows>=8 are discarded garbage)
    float accq[8], acck[8];
#pragma unroll
    for (int j = 0; j < 8; ++j) { accq[j] = 0.f; acck[j] = 0.f; }
#pragma unroll
    for (int pp = 0; pp < 4; ++pp) {
        int rr = 4 * frow + pp;
        if (rr > 31) rr = 31;
        s8v uq = *(const s8v*)(Qg + rr * 32 + fhalf * 8);
        s8v uk = *(const s8v*)(Kg + rr * 32 + fhalf * 8);
#pragma unroll
        for (int j = 0; j < 8; ++j) {
            accq[j] += b2f((bf16_t)uq[j]);
            acck[j] += b2f((bf16_t)uk[j]);
        }
    }
    s8v aqp, bkp;
#pragma unroll
    for (int j = 0; j < 8; ++j) {
        aqp[j] = (short)f2b(accq[j] * 0.25f);
        bkp[j] = (short)f2b(acck[j] * 0.25f);
    }
    // V load + LDS transpose staging
    {
        s8v v0 = *(const s8v*)(Vg + lane * 16);
        s8v v1 = *(const s8v*)(Vg + lane * 16 + 8);
        int pw = lane >> 1, ph0 = (lane & 1) * 16;
#pragma unroll
        for (int j = 0; j < 8; ++j) {
            *(bf16_t*)(P + VT + (ph0 + j) * 80 + pw * 2) = (bf16_t)(unsigned short)v0[j];
            *(bf16_t*)(P + VT + (ph0 + 8 + j) * 80 + pw * 2) = (bf16_t)(unsigned short)v1[j];
        }
    }
    // zero-fill pad regions (before the partial writes below; in-order LDS pipe)
    if (lane < 32) {
#pragma unroll
        for (int q = 0; q < 4; ++q) *(f4v*)(P + S1 + lane * 80 + q * 16) = zf;   // s1 rows, full 64B
#pragma unroll
        for (int q = 0; q < 3; ++q) *(f4v*)(P + KQ + lane * 80 + 16 + q * 16) = zf;  // kqvT k-pad
    } else if (lane < 40) {
#pragma unroll
        for (int q = 0; q < 4; ++q) *(f4v*)(P + S2 + (lane - 24) * 80 + q * 16) = zf;  // s2 rows 8..15
    }

    // stage 1&2 MFMAs (register inputs only)
    f4v s1a = __builtin_amdgcn_mfma_f32_16x16x32_bf16(aq0, bkp, zf, 0, 0, 0);
    f4v s1b = __builtin_amdgcn_mfma_f32_16x16x32_bf16(aq1, bkp, zf, 0, 0, 0);
    f4v s2a = __builtin_amdgcn_mfma_f32_16x16x32_bf16(aqp, bk0, zf, 0, 0, 0);
    f4v s2b = __builtin_amdgcn_mfma_f32_16x16x32_bf16(aqp, bk1, zf, 0, 0, 0);

    const float dsc = 0.0625f;  // 1/sqrt(256)
    // softmax s1 (rows 32, valid cols j<8) -> S1 bytes 0..15 of each row
    {
        int j = lane & 15;
#pragma unroll
        for (int t = 0; t < 2; ++t) {
            f4v av = t ? s1b : s1a;
#pragma unroll
            for (int r = 0; r < 4; ++r) {
                float x = av[r] * dsc;
                float m = x;
                m = fmaxf(m, __shfl_xor(m, 1));
                m = fmaxf(m, __shfl_xor(m, 2));
                m = fmaxf(m, __shfl_xor(m, 4));
                float e2 = __expf(x - m);
                float s = e2;
                s += __shfl_xor(s, 1);
                s += __shfl_xor(s, 2);
                s += __shfl_xor(s, 4);
                float p = e2 / s;
                if (j < 8) {
                    int row = t * 16 + fhalf * 4 + r;
                    *(bf16_t*)(P + S1 + row * 80 + j * 2) = f2b(p);
                }
            }
        }
    }
    // softmax s2 (valid rows i2<8, 32 cols across two tiles) -> S2 rows 0..7
#pragma unroll
    for (int r = 0; r < 4; ++r) {
        float xa = s2a[r] * dsc, xb = s2b[r] * dsc;
        float m = fmaxf(xa, xb);
        m = fmaxf(m, __shfl_xor(m, 1));
        m = fmaxf(m, __shfl_xor(m, 2));
        m = fmaxf(m, __shfl_xor(m, 4));
        m = fmaxf(m, __shfl_xor(m, 8));
        float ea = __expf(xa - m), eb = __expf(xb - m);
        float s = ea + eb;
        s += __shfl_xor(s, 1);
        s += __shfl_xor(s, 2);
        s += __shfl_xor(s, 4);
        s += __shfl_xor(s, 8);
        float inv = 1.f / s;
        if (lane < 32) {
            int row = fhalf * 4 + r;
            *(bf16_t*)(P + S2 + row * 80 + frow * 2) = f2b(ea * inv);
            *(bf16_t*)(P + S2 + row * 80 + (16 + frow) * 2) = f2b(eb * inv);
        }
    }
    __builtin_amdgcn_wave_barrier();
    // stage 3: kqv = s2·V -> write kqv^T into KQ (rows=ph, cols=i2)
    {
        s8v as2 = *(const s8v*)(P + S2 + frow * 80 + fbyte);
        s8v bv0 = *(const s8v*)(P + VT + frow * 80 + fbyte);
        s8v bv1 = *(const s8v*)(P + VT + (16 + frow) * 80 + fbyte);
        f4v k3a = __builtin_amdgcn_mfma_f32_16x16x32_bf16(as2, bv0, zf, 0, 0, 0);
        f4v k3b = __builtin_amdgcn_mfma_f32_16x16x32_bf16(as2, bv1, zf, 0, 0, 0);
        if (lane < 32) {
#pragma unroll
            for (int r = 0; r < 4; ++r) {
                int i2 = fhalf * 4 + r;
                *(bf16_t*)(P + KQ + frow * 80 + i2 * 2) = f2b(k3a[r]);
                *(bf16_t*)(P + KQ + (16 + frow) * 80 + i2 * 2) = f2b(k3b[r]);
            }
        }
    }
    __builtin_amdgcn_wave_barrier();
    // stage 4: out = s1·kqv  (k=8 zero-padded to 32)
    {
        s8v a40 = *(const s8v*)(P + S1 + frow * 80 + fbyte);
        s8v a41 = *(const s8v*)(P + S1 + (16 + frow) * 80 + fbyte);
        s8v b40 = *(const s8v*)(P + KQ + frow * 80 + fbyte);
        s8v b41 = *(const s8v*)(P + KQ + (16 + frow) * 80 + fbyte);
        f4v o00 = __builtin_amdgcn_mfma_f32_16x16x32_bf16(a40, b40, zf, 0, 0, 0);
        f4v o01 = __builtin_amdgcn_mfma_f32_16x16x32_bf16(a40, b41, zf, 0, 0, 0);
        f4v o10 = __builtin_amdgcn_mfma_f32_16x16x32_bf16(a41, b40, zf, 0, 0, 0);
        f4v o11 = __builtin_amdgcn_mfma_f32_16x16x32_bf16(a41, b41, zf, 0, 0, 0);
#pragma unroll
        for (int r = 0; r < 4; ++r) {
            int r0 = fhalf * 4 + r;
            *(bf16_t*)(P + VT + r0 * 80 + frow * 2) = f2b(o00[r]);
            *(bf16_t*)(P + VT + r0 * 80 + (16 + frow) * 2) = f2b(o01[r]);
            *(bf16_t*)(P + VT + (16 + r0) * 80 + frow * 2) = f2b(o10[r]);
            *(bf16_t*)(P + VT + (16 + r0) * 80 + (16 + frow) * 2) = f2b(o11[r]);
        }
    }
    __builtin_amdgcn_wave_barrier();
    {
        int i = lane >> 1, hh = (lane & 1) * 32;
        s8v r0 = *(const s8v*)(P + VT + i * 80 + hh);
        s8v r1 = *(const s8v*)(P + VT + i * 80 + hh + 16);
        *(s8v*)(A + base + lane * 16) = r0;
        *(s8v*)(A + base + lane * 16 + 8) = r1;
    }
}

// ta = X + A^T : A (B,C,S) -> add into X (B,S,C); optional fp32 att snapshot.
// Vectorized: tile 64c x 32s, s8v on both global sides; LDS row stride 80B
// (16B-aligned, bank advance 20/row -> 8-row gather conflict-free).
// XCD swizzle keeps batch affinity with attn (producer of Aa) and mm (consumer of X).
template <bool SNAP>
__global__ __launch_bounds__(256) void add_tr_k(const bf16_t* __restrict__ Aa, bf16_t* X,
                                                float* __restrict__ att) {
    __shared__ bf16_t Tl[64 * 40];
    const int id = blockIdx.x + 32 * (blockIdx.y + 4 * blockIdx.z);  // 4096 blocks
    const int logical = (id & 7) * 512 + (id >> 3);
    const int sx = logical & 31, cy = (logical >> 5) & 3, b = logical >> 7;
    const int c0 = cy * 64, s0 = sx * 32;
    const int t = threadIdx.x;

    // load A tile: 64 c-rows x 32 s (64B/row), 4 threads per row
    {
        int cr = t >> 2, so = (t & 3) * 8;
        s8v v = *(const s8v*)(Aa + ((size_t)(b * 256 + c0 + cr)) * 1024 + s0 + so);
        *(s8v*)(Tl + cr * 40 + so) = v;
    }
    __syncthreads();
    // X side: 32 s-rows x 64 c (128B/row), 8 threads per row
    {
        int sr = t >> 3, co = (t & 7) * 8;
        size_t idx = ((size_t)(b * 1024 + s0 + sr)) * 256 + c0 + co;
        s8v xv = *(const s8v*)(X + idx);
        s8v nx;
        f4v lo, hi;
#pragma unroll
        for (int j = 0; j < 8; ++j) {
            float v = b2f((bf16_t)xv[j]) + b2f(Tl[(co + j) * 40 + sr]);
            nx[j] = (short)f2b(v);
            if (j < 4) lo[j] = v; else hi[j - 4] = v;
        }
        *(s8v*)(X + idx) = nx;
        if constexpr (SNAP) {
            *(f4v*)(att + idx) = lo;
            *(f4v*)(att + idx + 4) = hi;
        }
    }
}

// ---------------- launch ----------------

extern "C" void kernel_launch(void* const* d_in, const int* in_sizes, int n_in,
                              void* d_out, int out_size, void* d_ws, size_t ws_size,
                              hipStream_t stream) {
    const float* image  = (const float*)d_in[0];
    const float* conv_w = (const float*)d_in[1];
    const float* conv_b = (const float*)d_in[2];
    const float* feat_w = (const float*)d_in[3];
    const float* feat_b = (const float*)d_in[4];
    const float* ln_s   = (const float*)d_in[5];
    const float* ln_b   = (const float*)d_in[6];
    const float* wq     = (const float*)d_in[7];
    const float* bq     = (const float*)d_in[8];
    const float* wk     = (const float*)d_in[9];
    const float* bk     = (const float*)d_in[10];
    const float* wv     = (const float*)d_in[11];
    const float* bv     = (const float*)d_in[12];
    const float* wf     = (const float*)d_in[13];
    const float* bfv    = (const float*)d_in[14];
    const float* wa     = (const float*)d_in[15];
    const float* ba     = (const float*)d_in[16];
    float* out = (float*)d_out;

    char* p = (char*)d_ws;
    const size_t MB16 = (size_t)B_ * S_ * C_ * sizeof(bf16_t);  // 16777216
    float* fw    = (float*)p;  p += 1024;
    float* fb    = (float*)p;  p += 1024;
    float* PART  = (float*)p;  p += 2097152;   // 32768 rows x 8 float2 (64B/row)
    float* csum  = (float*)p;  p += 24576;
    float* bias2 = (float*)p;  p += 24576;
    bf16_t* WT = (bf16_t*)p;   p += (size_t)48 * 65536 * 2;
    bf16_t* X  = (bf16_t*)p;   p += MB16;
    bf16_t* T1 = (bf16_t*)p;   p += MB16;  // attn-delta
    bf16_t* T2 = (bf16_t*)p;   p += MB16;  // tn2
    bf16_t* Qb = (bf16_t*)p;   p += MB16;
    bf16_t* Kb = (bf16_t*)p;   p += MB16;
    bf16_t* Vb = (bf16_t*)p;   p += MB16;
    size_t needed = (size_t)(p - (char*)d_ws);
    if (ws_size < needed) Vb = (bf16_t*)d_out;  // out slot0 only written at the very end

    fuse_wb_k<<<1, 256, 0, stream>>>(conv_w, conv_b, feat_w, feat_b, fw, fb);
    wtrans_k<<<dim3(8, 8, 48), 256, 0, stream>>>(wq, wk, wv, wf, wa, ln_s, WT);
    colsum_k<<<dim3(3, 8), 256, 0, stream>>>(WT, wq, wk, wv, bq, bk, bv, ln_b, csum, bias2);
    embed_k<<<8192, 256, 0, stream>>>(image, fw, fb, X, PART);

    const size_t slot = (size_t)B_ * S_ * C_;

    for (int l = 0; l < L_; ++l) {
        const bf16_t* WTl = WT + (size_t)l * 6 * 65536;
        int snap = (l == 2) ? 0 : (l == 4) ? 1 : (l == 6) ? 2 : -1;

        mm_k<0, false><<<dim3(12, 8, 32), 256, 0, stream>>>(
            X, WTl, nullptr, bias2 + l * 768, csum + l * 768, PART, nullptr,
            Qb, Kb, Vb, nullptr, nullptr);
        attn_k<<<2048, 256, 0, stream>>>(Qb, Kb, Vb, T1);
        if (snap >= 0)
            add_tr_k<true><<<dim3(32, 4, 32), 256, 0, stream>>>(T1, X, out + (size_t)(4 + snap) * slot);
        else
            add_tr_k<false><<<dim3(32, 4, 32), 256, 0, stream>>>(T1, X, nullptr);
        // X is now ta
        mm_k<1, false><<<dim3(4, 8, 32), 256, 0, stream>>>(
            X, WTl + 4 * 65536, WTl + 5 * 65536, ba + l * 512, nullptr, nullptr, X,
            T2, nullptr, nullptr, nullptr, nullptr);
        float* hid = (snap >= 0) ? out + (size_t)(1 + snap) * slot : (l == 7 ? out : nullptr);
        if (hid)
            mm_k<2, true><<<dim3(4, 8, 32), 256, 0, stream>>>(
                T2, WTl + 3 * 65536, nullptr, bfv + l * 256, nullptr, nullptr, X,
                X, nullptr, nullptr, hid, PART);
        else
            mm_k<2, false><<<dim3(4, 8, 32), 256, 0, stream>>>(
                T2, WTl + 3 * 65536, nullptr, bfv + l * 256, nullptr, nullptr, X,
                X, nullptr, nullptr, nullptr, PART);
    }
}